// Round 3
// baseline (33.241 us; speedup 1.0000x reference)
//
#include <hip/hip_runtime.h>

// N=8192, d_model=2048, h=16, d_k=128.
// softmax over size-1 axis == 1.0, so head_out[h,n,:] = v_proj[h,0,:] for all n.
// out[n][m] = r[m]  where  r = (vp @ Wo),  vp[h*128+k] = sum_d v_param[d]*Wv[h,d,k].
//
// Stages (ws: vp[2048] fp32 @0, r[2048] fp32 @8KB, both zeroed per call):
//   memset 16KB
//   K1: atomicAdd-accumulate vp      (reads Wv, 16 MB)
//   K2: atomicAdd-accumulate r       (reads Wo, 16 MB)
//   K3: pure broadcast of r          (writes 64 MB)

#define DM 2048
#define H  16
#define DK 128

// K1: grid (64 d-chunks of 32, 16 heads), 128 threads (k).
__global__ __launch_bounds__(128) void k_vproj(const float* __restrict__ Wv,
                                               const float* __restrict__ vparam,
                                               float* __restrict__ vp) {
    const int c = blockIdx.x;   // 0..63
    const int h = blockIdx.y;   // 0..15
    const int k = threadIdx.x;  // 0..127
    const float* wp = Wv + ((size_t)h * DM + (size_t)c * 32) * DK + k;
    const float* vq = vparam + c * 32;
    float acc = 0.f;
#pragma unroll
    for (int d = 0; d < 32; ++d) {
        acc += vq[d] * wp[(size_t)d * DK];
    }
    atomicAdd(&vp[h * DK + k], acc);
}

// K2: grid (8 m-blocks of 256, 128 j-chunks of 16), 256 threads.
__global__ __launch_bounds__(256) void k_rowproj(const float* __restrict__ vp,
                                                 const float* __restrict__ Wo,
                                                 float* __restrict__ r) {
    const int mb = blockIdx.x;  // 0..7
    const int jc = blockIdx.y;  // 0..127
    const int t  = threadIdx.x; // 0..255
    const int m  = mb * 256 + t;
    const float* wo = Wo + (size_t)(jc * 16) * DM + m;
    float acc = 0.f;
#pragma unroll
    for (int jl = 0; jl < 16; ++jl) {
        acc += vp[jc * 16 + jl] * wo[(size_t)jl * DM];
    }
    atomicAdd(&r[m], acc);
}

// K3: pure broadcast. grid (2 col-halves, 256 row-groups of 32), 256 threads.
// One float4 read of r per thread (L2-hot), 32 coalesced 4KB row stores.
__global__ __launch_bounds__(256) void k_bcast(const float* __restrict__ r,
                                               float* __restrict__ out) {
    const int cs = blockIdx.x;  // 0..1
    const int rg = blockIdx.y;  // 0..255
    const int t  = threadIdx.x; // 0..255
    const float4 v = ((const float4*)r)[cs * 256 + t];
    float4* out4 = (float4*)out + (size_t)(rg * 32) * (DM / 4) + cs * 256 + t;
#pragma unroll
    for (int n = 0; n < 32; ++n) {
        out4[(size_t)n * (DM / 4)] = v;
    }
}

extern "C" void kernel_launch(void* const* d_in, const int* in_sizes, int n_in,
                              void* d_out, int out_size, void* d_ws, size_t ws_size,
                              hipStream_t stream) {
    // inputs: 0=q, 1=Wq, 2=Wk, 3=Wv, 4=k_param, 5=v_param, 6=Wo (all fp32)
    const float* Wv     = (const float*)d_in[3];
    const float* vparam = (const float*)d_in[5];
    const float* Wo     = (const float*)d_in[6];
    float* out = (float*)d_out;

    float* vp = (float*)d_ws;        // 2048 floats
    float* r  = vp + DM;             // 2048 floats

    hipMemsetAsync(d_ws, 0, 2 * DM * sizeof(float), stream);
    k_vproj  <<<dim3(64, H),   128, 0, stream>>>(Wv, vparam, vp);
    k_rowproj<<<dim3(8, 128),  256, 0, stream>>>(vp, Wo, r);
    k_bcast  <<<dim3(2, 256),  256, 0, stream>>>(r, out);
}

// Round 5
// 26.367 us; speedup vs baseline: 1.2607x; 1.2607x over previous
//
#include <hip/hip_runtime.h>

// N=8192, d_model=2048, h=16, d_k=128.
// softmax over a size-1 axis == 1.0 exactly -> head_out[h,n,:] = v_proj[h,0,:].
// out[n][m] = r[m],  r = vp @ Wo,  vp[h*128+k] = sum_d v_param[d]*Wv[h,d,k].
//
// Two nodes:
//  N1: Wv (16 MB, coalesced) -> part1[8][2048] vp-partials (64 KB)
//  N2: per-block: stage vp (reduce part1) -> GEMV r for a 32-col slice of Wo
//      -> broadcast-store 2048x32 output tile.  (reads 16 MB Wo + writes 64 MB)

#define DM 2048
#define H  16
#define DK 128

// N1: grid (16 heads, 8 d-quarters of 256), 1024 threads.
// thread: k = t&127, dg = t>>7; sums 32 d's, fully coalesced (256B/wave/load).
__global__ __launch_bounds__(1024) void k_vp(const float* __restrict__ Wv,
                                             const float* __restrict__ vparam,
                                             float* __restrict__ part1) {
    const int h  = blockIdx.x;
    const int dq = blockIdx.y;
    const int t  = threadIdx.x;
    const int k  = t & 127;
    const int dg = t >> 7;              // 0..7
    const int d0 = dq * 256 + dg * 32;
    const float* wp = Wv + ((size_t)h * DM + d0) * DK + k;
    float acc = 0.f;
#pragma unroll
    for (int i = 0; i < 32; ++i) acc += vparam[d0 + i] * wp[(size_t)i * DK];
    __shared__ float sred[8][128];
    sred[dg][k] = acc;
    __syncthreads();
    if (t < 128) {
        float s = 0.f;
#pragma unroll
        for (int g = 0; g < 8; ++g) s += sred[g][t];
        part1[dq * DM + h * DK + t] = s;
    }
}

// N2: grid (64 col-slices of 32, 4 row-groups of 2048), 1024 threads.
__global__ __launch_bounds__(1024) void k_out(const float* __restrict__ part1,
                                              const float* __restrict__ Wo,
                                              float* __restrict__ out) {
    const int ms = blockIdx.x;          // 0..63: cols ms*32 .. +32
    const int rg = blockIdx.y;          // 0..3 : rows rg*2048 .. +2048
    const int t  = threadIdx.x;

    // stage full vp (2048) into LDS: reduce the 8 part1 partials
    __shared__ float vp_s[DM];
#pragma unroll
    for (int rpt = 0; rpt < 2; ++rpt) {
        const int j = rpt * 1024 + t;
        float s = 0.f;
#pragma unroll
        for (int dq = 0; dq < 8; ++dq) s += part1[dq * DM + j];
        vp_s[j] = s;
    }
    __syncthreads();

    // GEMV partial: c = t&31 (col), jg = t>>5 (32 j-groups of 64)
    const int c  = t & 31;
    const int jg = t >> 5;
    const float* wo = Wo + (size_t)(jg * 64) * DM + ms * 32 + c;
    float acc = 0.f;
#pragma unroll 16
    for (int i = 0; i < 64; ++i) acc += vp_s[jg * 64 + i] * wo[(size_t)i * DM];

    __shared__ float red[32][33];       // padded: conflict-free column reduce
    red[jg][c] = acc;
    __syncthreads();
    __shared__ float r_s[32];
    if (t < 32) {
        float s = 0.f;
#pragma unroll
        for (int g = 0; g < 32; ++g) s += red[g][t];
        r_s[t] = s;
    }
    __syncthreads();

    // broadcast-store this block's 2048x32 tile
    const float val = r_s[c];
    const int rr = t >> 5;              // 0..31
    float* op = out + ((size_t)rg * 2048 + rr) * DM + ms * 32 + c;
#pragma unroll
    for (int i = 0; i < 64; ++i) {
        op[(size_t)i * 32 * DM] = val;
    }
}

extern "C" void kernel_launch(void* const* d_in, const int* in_sizes, int n_in,
                              void* d_out, int out_size, void* d_ws, size_t ws_size,
                              hipStream_t stream) {
    // inputs: 0=q, 1=Wq, 2=Wk, 3=Wv, 4=k_param, 5=v_param, 6=Wo (all fp32)
    const float* Wv     = (const float*)d_in[3];
    const float* vparam = (const float*)d_in[5];
    const float* Wo     = (const float*)d_in[6];
    float* out = (float*)d_out;

    float* part1 = (float*)d_ws;        // 8*2048 floats = 64 KB

    k_vp <<<dim3(H, 8),  1024, 0, stream>>>(Wv, vparam, part1);
    k_out<<<dim3(64, 4), 1024, 0, stream>>>(part1, Wo, out);
}